// Round 2
// baseline (1255.551 us; speedup 1.0000x reference)
//
#include <hip/hip_runtime.h>

#define N_NODES 50000
#define M_EDGES 10000
#define NNZ_TOT 400000
#define DF      128
#define HID     256
#define NOUT    40

// ---------------------------------------------------------------- CSR build
__global__ __launch_bounds__(256) void count_kernel(const int* __restrict__ V, const int* __restrict__ E,
                                                    int* __restrict__ cntV, int* __restrict__ cntE) {
  int i = blockIdx.x * 256 + threadIdx.x;
  if (i < NNZ_TOT) {
    int v = V[i]; v = (v < 0) ? 0 : (v >= N_NODES ? N_NODES - 1 : v);
    int e = E[i]; e = (e < 0) ? 0 : (e >= M_EDGES ? M_EDGES - 1 : e);
    atomicAdd(&cntV[v], 1);
    atomicAdd(&cntE[e], 1);
  }
}

// single-block exclusive scan; writes rowptr[0..n]; converts cnt[] in place into
// the running cursor array for the fill pass (alias-safe: thread-local temp).
__global__ __launch_bounds__(1024) void scan_kernel(int* __restrict__ cnt, int n,
                                                    int* __restrict__ rowptr) {
  __shared__ int sm[1024];
  int chunk = (n + 1023) >> 10;
  int beg = threadIdx.x * chunk;
  int end = beg + chunk;
  if (beg > n) beg = n;
  if (end > n) end = n;
  int s = 0;
  for (int i = beg; i < end; ++i) s += cnt[i];
  sm[threadIdx.x] = s;
  __syncthreads();
  for (int off = 1; off < 1024; off <<= 1) {
    int t = (threadIdx.x >= (unsigned)off) ? sm[threadIdx.x - off] : 0;
    __syncthreads();
    sm[threadIdx.x] += t;
    __syncthreads();
  }
  int run = sm[threadIdx.x] - s;   // exclusive prefix of this thread's chunk
  for (int i = beg; i < end; ++i) {
    int c = cnt[i];                // read BEFORE overwrite (cnt doubles as cursor)
    rowptr[i] = run;
    cnt[i] = run;
    run += c;
  }
  if (threadIdx.x == 1023) rowptr[n] = sm[1023];
}

__global__ __launch_bounds__(256) void fill_kernel(const int* __restrict__ V, const int* __restrict__ E,
                                                   int* __restrict__ curV, int* __restrict__ curE,
                                                   int* __restrict__ colE, int* __restrict__ colV) {
  int i = blockIdx.x * 256 + threadIdx.x;
  if (i < NNZ_TOT) {
    int v = V[i]; v = (v < 0) ? 0 : (v >= N_NODES ? N_NODES - 1 : v);
    int e = E[i]; e = (e < 0) ? 0 : (e >= M_EDGES ? M_EDGES - 1 : e);
    int p = atomicAdd(&curV[v], 1);
    colE[p] = e;                    // edges grouped by node
    int q = atomicAdd(&curE[e], 1);
    colV[q] = v;                    // nodes grouped by edge
  }
}

__global__ __launch_bounds__(256) void edge_stats_kernel(const int* __restrict__ rowptrE,
                                                         float* __restrict__ invDE) {
  int e = blockIdx.x * 256 + threadIdx.x;
  if (e < M_EDGES) invDE[e] = 1.0f / (float)(rowptrE[e + 1] - rowptrE[e]);
}

__global__ __launch_bounds__(256) void node_stats_kernel(const int* __restrict__ rowptrV,
                                                         const int* __restrict__ colE,
                                                         const float* __restrict__ invDE,
                                                         float* __restrict__ invD,
                                                         float* __restrict__ invSqrtD,
                                                         float* __restrict__ rv) {
  int v = blockIdx.x * 256 + threadIdx.x;
  if (v < N_NODES) {
    int b = rowptrV[v], e = rowptrV[v + 1];
    float d = (float)(e - b);
    invD[v] = 1.0f / d;
    invSqrtD[v] = 1.0f / sqrtf(d);
    float r = 0.0f;
    for (int j = b; j < e; ++j) r += invDE[colE[j]];
    rv[v] = r;   // r_v = sum_{e ∋ v} 1/DE_e  (data-independent phi weight)
  }
}

// ------------------------------------------------------------- phi(X) setup
// partials[block] = sum over 4 nodes of ||X_v||^2 * invD_v * r_v
__global__ __launch_bounds__(256) void phi0_kernel(const float* __restrict__ X,
                                                   const float* __restrict__ invD,
                                                   const float* __restrict__ rv,
                                                   float* __restrict__ partials) {
  __shared__ float red[4];
  int w = threadIdx.x >> 6;
  int v = (blockIdx.x << 2) + w;
  v = __builtin_amdgcn_readfirstlane(v);
  int lane = threadIdx.x & 63;
  float2 xv = *(const float2*)(X + (size_t)v * DF + lane * 2);
  float q = xv.x * xv.x + xv.y * xv.y;
#pragma unroll
  for (int off = 32; off > 0; off >>= 1) q += __shfl_down(q, off, 64);
  if (lane == 0) red[w] = q * invD[v] * rv[v];
  __syncthreads();
  if (threadIdx.x == 0) partials[blockIdx.x] = red[0] + red[1] + red[2] + red[3];
}

__global__ __launch_bounds__(1024) void finalize_kernel(const float* __restrict__ partials, int n,
                                                        float* __restrict__ scalars, int idx) {
  __shared__ float red[1024];
  float s = 0.0f;
  for (int i = threadIdx.x; i < n; i += 1024) s += partials[i];
  red[threadIdx.x] = s;
  __syncthreads();
  for (int off = 512; off > 0; off >>= 1) {
    if (threadIdx.x < (unsigned)off) red[threadIdx.x] += red[threadIdx.x + off];
    __syncthreads();
  }
  if (threadIdx.x == 0) scalars[idx] = 1.0f / (2.0f * sqrtf(red[0]));  // s = 1/phi
}

// ------------------------------------------------------------- V2E pass
// one wave per hyperedge; Pe[e,d] = sqrt( (sum_{v in e} A[v,d]^2 / D_v) / DE_e )   (scale deferred)
__global__ __launch_bounds__(256) void v2e_kernel(const float* __restrict__ Ain, float* __restrict__ Pe,
                                                  const int* __restrict__ rowptrE,
                                                  const int* __restrict__ colV,
                                                  const float* __restrict__ invD,
                                                  const float* __restrict__ invDE) {
  int e = (blockIdx.x << 2) + (threadIdx.x >> 6);
  e = __builtin_amdgcn_readfirstlane(e);
  int lane = threadIdx.x & 63;
  int beg = rowptrE[e], end = rowptrE[e + 1];
  float ax = 0.0f, ay = 0.0f;
  int v = colV[beg];
  for (int j = beg; j < end; ++j) {
    int vn = (j + 1 < end) ? colV[j + 1] : 0;   // prefetch next index
    float id = invD[v];
    float2 a = *(const float2*)(Ain + (size_t)v * DF + lane * 2);
    ax += a.x * a.x * id;
    ay += a.y * a.y * id;
    v = vn;
  }
  float de = invDE[e];
  float2 o;
  o.x = sqrtf(ax * de);
  o.y = sqrtf(ay * de);
  *(float2*)(Pe + (size_t)e * DF + lane * 2) = o;
}

// ------------------------------------------------------------- E2V + G + phi partials
// G[v,d] = 0.9*s_prev*invSqrtD_v*sum_{e ∋ v} Pe[e,d] + 0.1*s0*X[v,d];  A <- G
// partials[block] = sum_nodes ||G_v||^2 * invD_v * r_v
__global__ __launch_bounds__(256) void e2v_kernel(const float* __restrict__ Pe, const float* __restrict__ X,
                                                  float* __restrict__ A,
                                                  const int* __restrict__ rowptrV,
                                                  const int* __restrict__ colE,
                                                  const float* __restrict__ invSqrtD,
                                                  const float* __restrict__ invD,
                                                  const float* __restrict__ rv,
                                                  const float* __restrict__ scalars, int sidx,
                                                  float* __restrict__ partials) {
  __shared__ float red[4];
  int w = threadIdx.x >> 6;
  int v = (blockIdx.x << 2) + w;
  v = __builtin_amdgcn_readfirstlane(v);
  int lane = threadIdx.x & 63;
  int beg = rowptrV[v], end = rowptrV[v + 1];
  float tx = 0.0f, ty = 0.0f;
  int e = colE[beg];
  for (int j = beg; j < end; ++j) {
    int en = (j + 1 < end) ? colE[j + 1] : 0;
    float2 p = *(const float2*)(Pe + (size_t)e * DF + lane * 2);
    tx += p.x;
    ty += p.y;
    e = en;
  }
  float sprev = scalars[sidx];
  float s0 = scalars[0];
  float c1 = 0.9f * sprev * invSqrtD[v];
  float c0 = 0.1f * s0;
  float2 xv = *(const float2*)(X + (size_t)v * DF + lane * 2);
  float gx = c1 * tx + c0 * xv.x;
  float gy = c1 * ty + c0 * xv.y;
  float2 g; g.x = gx; g.y = gy;
  *(float2*)(A + (size_t)v * DF + lane * 2) = g;
  float q = gx * gx + gy * gy;
#pragma unroll
  for (int off = 32; off > 0; off >>= 1) q += __shfl_down(q, off, 64);
  if (lane == 0) red[w] = q * invD[v] * rv[v];
  __syncthreads();
  if (threadIdx.x == 0) partials[blockIdx.x] = red[0] + red[1] + red[2] + red[3];
}

// ------------------------------------------------------------- fused decoder
// per block: 64 nodes. GEMM1 (128->256) f32 reg-tiled + LayerNorm + ReLU + GEMM2 (256->40)
__global__ __launch_bounds__(256) void decoder_kernel(const float* __restrict__ A,
                                                      const float* __restrict__ scalars,
                                                      const float* __restrict__ W1, const float* __restrict__ b1,
                                                      const float* __restrict__ gam, const float* __restrict__ bet,
                                                      const float* __restrict__ W2, const float* __restrict__ b2,
                                                      float* __restrict__ out) {
  __shared__ float buf[14464];            // 57,856 B: Ftile[64][128] aliased with hch[64][66] + W2s[256][40]
  float* Ft = buf;
  const int tid = threadIdx.x;
  const int node0 = blockIdx.x * 64;
  const float s = scalars[10];

  // stage F tile = s * A rows (zero-pad OOB nodes)
  const float4* Av = (const float4*)(A + (size_t)node0 * DF);
  for (int i = tid; i < 2048; i += 256) {
    int nd = i >> 5;                       // 32 float4 per row
    float4 f;
    if (node0 + nd < N_NODES) f = Av[i];
    else f = make_float4(0.f, 0.f, 0.f, 0.f);
    f.x *= s; f.y *= s; f.z *= s; f.w *= s;
    ((float4*)Ft)[i] = f;
  }
  __syncthreads();

  const int rt = tid >> 5;                 // 0..7  -> node group of 8
  const int ct = tid & 31;                 // 0..31 -> hid group of 8
  float bias[8], g8[8], be8[8];
#pragma unroll
  for (int j = 0; j < 8; ++j) {
    bias[j] = b1[ct * 8 + j];
    g8[j] = gam[ct * 8 + j];
    be8[j] = bet[ct * 8 + j];
  }
  float acc[8][8];
#pragma unroll
  for (int i = 0; i < 8; ++i)
#pragma unroll
    for (int j = 0; j < 8; ++j) acc[i][j] = bias[j];

  for (int k4 = 0; k4 < 32; ++k4) {
    float4 a4[8];
#pragma unroll
    for (int i = 0; i < 8; ++i) a4[i] = *(const float4*)(&Ft[(rt * 8 + i) * 128 + k4 * 4]);
#pragma unroll
    for (int kk = 0; kk < 4; ++kk) {
      const float* wrow = W1 + (k4 * 4 + kk) * HID + ct * 8;
      float4 b0 = *(const float4*)(wrow);
      float4 b1v = *(const float4*)(wrow + 4);
      float bb[8] = {b0.x, b0.y, b0.z, b0.w, b1v.x, b1v.y, b1v.z, b1v.w};
#pragma unroll
      for (int i = 0; i < 8; ++i) {
        float av = (kk == 0) ? a4[i].x : (kk == 1) ? a4[i].y : (kk == 2) ? a4[i].z : a4[i].w;
#pragma unroll
        for (int j = 0; j < 8; ++j) acc[i][j] += av * bb[j];
      }
    }
  }

  // LayerNorm over 256 hid dims (32 lanes of same rt hold the row) + ReLU
#pragma unroll
  for (int i = 0; i < 8; ++i) {
    float s1 = 0.f, s2 = 0.f;
#pragma unroll
    for (int j = 0; j < 8; ++j) { s1 += acc[i][j]; s2 += acc[i][j] * acc[i][j]; }
#pragma unroll
    for (int off = 16; off > 0; off >>= 1) {
      s1 += __shfl_xor(s1, off, 64);
      s2 += __shfl_xor(s2, off, 64);
    }
    float mu = s1 * (1.0f / 256.0f);
    float var = s2 * (1.0f / 256.0f) - mu * mu;
    float rs = rsqrtf(var + 1e-5f);
#pragma unroll
    for (int j = 0; j < 8; ++j)
      acc[i][j] = fmaxf(0.0f, (acc[i][j] - mu) * rs * g8[j] + be8[j]);
  }
  __syncthreads();   // Ftile dead from here

  float* hch = buf;                        // [64][66] padded chunk of h
  float* W2s = buf + 4224;                 // [256][40]
  for (int i = tid; i < HID * NOUT; i += 256) W2s[i] = W2[i];

  const int n_l = tid >> 2;                // 0..63 node
  const int og = tid & 3;                  // 4 groups of 10 outputs
  float oacc[10];
#pragma unroll
  for (int j = 0; j < 10; ++j) oacc[j] = b2[og * 10 + j];

  for (int c = 0; c < 4; ++c) {            // 4 chunks of 64 hid dims
    if ((ct >> 3) == c) {
      int c8 = (ct & 7) * 8;
#pragma unroll
      for (int i = 0; i < 8; ++i)
#pragma unroll
        for (int j = 0; j < 8; ++j) hch[(rt * 8 + i) * 66 + c8 + j] = acc[i][j];
    }
    __syncthreads();
    for (int kk = 0; kk < 64; ++kk) {
      float hv = hch[n_l * 66 + kk];
      const float* w = W2s + (c * 64 + kk) * NOUT + og * 10;
#pragma unroll
      for (int j = 0; j < 10; ++j) oacc[j] += hv * w[j];
    }
    __syncthreads();
  }

  int node = node0 + n_l;
  if (node < N_NODES) {
#pragma unroll
    for (int j = 0; j < 10; ++j) out[(size_t)node * NOUT + og * 10 + j] = oacc[j];
  }
}

// ---------------------------------------------------------------- launch
extern "C" void kernel_launch(void* const* d_in, const int* in_sizes, int n_in,
                              void* d_out, int out_size, void* d_ws, size_t ws_size,
                              hipStream_t stream) {
  (void)in_sizes; (void)n_in; (void)out_size; (void)ws_size;
  const float* x = (const float*)d_in[0];
  const int* he = (const int*)d_in[1];
  const int* V = he;
  const int* E = he + NNZ_TOT;
  const float* W1 = (const float*)d_in[2];
  const float* b1 = (const float*)d_in[3];
  const float* gam = (const float*)d_in[4];
  const float* bet = (const float*)d_in[5];
  const float* W2 = (const float*)d_in[6];
  const float* b2 = (const float*)d_in[7];
  float* out = (float*)d_out;

  // ws budget matters: keep total < 32 MiB. Pe (5.12 MB) lives in d_out (8 MB),
  // which is only written by the decoder (last kernel), after Pe is dead.
  float* Pe = (float*)d_out;

  char* p = (char*)d_ws;
  auto nextp = [&](size_t bytes) -> char* {
    char* r = p;
    p += (bytes + 255) & ~(size_t)255;
    return r;
  };
  int* cntV      = (int*)nextp((size_t)(N_NODES + M_EDGES) * 4);  // doubles as cursor after scan
  int* cntE      = cntV + N_NODES;
  int* rowptrV   = (int*)nextp((size_t)(N_NODES + 1) * 4);
  int* rowptrE   = (int*)nextp((size_t)(M_EDGES + 1) * 4);
  int* colE      = (int*)nextp((size_t)NNZ_TOT * 4);
  int* colV      = (int*)nextp((size_t)NNZ_TOT * 4);
  float* invD    = (float*)nextp((size_t)N_NODES * 4);
  float* invSqrtD= (float*)nextp((size_t)N_NODES * 4);
  float* rv      = (float*)nextp((size_t)N_NODES * 4);
  float* invDE   = (float*)nextp((size_t)M_EDGES * 4);
  float* A       = (float*)nextp((size_t)N_NODES * DF * 4);
  float* partials= (float*)nextp((size_t)(N_NODES / 4) * 4);
  float* scalars = (float*)nextp(16 * 4);
  // total ~28.6 MiB

  const int NBLK_NNZ = (NNZ_TOT + 255) / 256;

  hipMemsetAsync(cntV, 0, (size_t)(N_NODES + M_EDGES) * 4, stream);
  count_kernel<<<NBLK_NNZ, 256, 0, stream>>>(V, E, cntV, cntE);
  scan_kernel<<<1, 1024, 0, stream>>>(cntV, N_NODES, rowptrV);
  scan_kernel<<<1, 1024, 0, stream>>>(cntE, M_EDGES, rowptrE);
  fill_kernel<<<NBLK_NNZ, 256, 0, stream>>>(V, E, cntV, cntE, colE, colV);
  edge_stats_kernel<<<(M_EDGES + 255) / 256, 256, 0, stream>>>(rowptrE, invDE);
  node_stats_kernel<<<(N_NODES + 255) / 256, 256, 0, stream>>>(rowptrV, colE, invDE,
                                                               invD, invSqrtD, rv);
  phi0_kernel<<<N_NODES / 4, 256, 0, stream>>>(x, invD, rv, partials);
  finalize_kernel<<<1, 1024, 0, stream>>>(partials, N_NODES / 4, scalars, 0);

  for (int k = 1; k <= 10; ++k) {
    v2e_kernel<<<M_EDGES / 4, 256, 0, stream>>>((k == 1) ? x : (const float*)A, Pe,
                                                rowptrE, colV, invD, invDE);
    e2v_kernel<<<N_NODES / 4, 256, 0, stream>>>(Pe, x, A, rowptrV, colE, invSqrtD, invD, rv,
                                                scalars, k - 1, partials);
    finalize_kernel<<<1, 1024, 0, stream>>>(partials, N_NODES / 4, scalars, k);
  }

  decoder_kernel<<<(N_NODES + 63) / 64, 256, 0, stream>>>(A, scalars, W1, b1, gam, bet, W2, b2, out);
}

// Round 3
// 1245.994 us; speedup vs baseline: 1.0077x; 1.0077x over previous
//
#include <hip/hip_runtime.h>

#define N_NODES 50000
#define M_EDGES 10000
#define NNZ_TOT 400000
#define DF      128
#define HID     256
#define NOUT    40

// ---------------------------------------------------------------- CSR build
__global__ __launch_bounds__(256) void count_kernel(const int* __restrict__ V, const int* __restrict__ E,
                                                    int* __restrict__ cntV, int* __restrict__ cntE) {
  int i = blockIdx.x * 256 + threadIdx.x;
  if (i < NNZ_TOT) {
    int v = V[i]; v = (v < 0) ? 0 : (v >= N_NODES ? N_NODES - 1 : v);
    int e = E[i]; e = (e < 0) ? 0 : (e >= M_EDGES ? M_EDGES - 1 : e);
    atomicAdd(&cntV[v], 1);
    atomicAdd(&cntE[e], 1);
  }
}

// single-block exclusive scan; writes rowptr[0..n]; converts cnt[] in place into
// the running cursor array for the fill pass (alias-safe: thread-local temp).
__global__ __launch_bounds__(1024) void scan_kernel(int* __restrict__ cnt, int n,
                                                    int* __restrict__ rowptr) {
  __shared__ int sm[1024];
  int chunk = (n + 1023) >> 10;
  int beg = threadIdx.x * chunk;
  int end = beg + chunk;
  if (beg > n) beg = n;
  if (end > n) end = n;
  int s = 0;
  for (int i = beg; i < end; ++i) s += cnt[i];
  sm[threadIdx.x] = s;
  __syncthreads();
  for (int off = 1; off < 1024; off <<= 1) {
    int t = (threadIdx.x >= (unsigned)off) ? sm[threadIdx.x - off] : 0;
    __syncthreads();
    sm[threadIdx.x] += t;
    __syncthreads();
  }
  int run = sm[threadIdx.x] - s;
  for (int i = beg; i < end; ++i) {
    int c = cnt[i];                // read BEFORE overwrite (cnt doubles as cursor)
    rowptr[i] = run;
    cnt[i] = run;
    run += c;
  }
  if (threadIdx.x == 1023) rowptr[n] = sm[1023];
}

__global__ __launch_bounds__(256) void fill_kernel(const int* __restrict__ V, const int* __restrict__ E,
                                                   int* __restrict__ curV, int* __restrict__ curE,
                                                   int* __restrict__ colE, int* __restrict__ colV) {
  int i = blockIdx.x * 256 + threadIdx.x;
  if (i < NNZ_TOT) {
    int v = V[i]; v = (v < 0) ? 0 : (v >= N_NODES ? N_NODES - 1 : v);
    int e = E[i]; e = (e < 0) ? 0 : (e >= M_EDGES ? M_EDGES - 1 : e);
    int p = atomicAdd(&curV[v], 1);
    colE[p] = e;                    // edges grouped by node
    int q = atomicAdd(&curE[e], 1);
    colV[q] = v;                    // nodes grouped by edge
  }
}

__global__ __launch_bounds__(256) void edge_stats_kernel(const int* __restrict__ rowptrE,
                                                         float* __restrict__ invDE) {
  int e = blockIdx.x * 256 + threadIdx.x;
  if (e < M_EDGES) invDE[e] = 1.0f / (float)(rowptrE[e + 1] - rowptrE[e]);
}

__global__ __launch_bounds__(256) void node_stats_kernel(const int* __restrict__ rowptrV,
                                                         const int* __restrict__ colE,
                                                         const float* __restrict__ invDE,
                                                         float* __restrict__ invSqrtD,
                                                         float* __restrict__ rv) {
  int v = blockIdx.x * 256 + threadIdx.x;
  if (v < N_NODES) {
    int b = rowptrV[v], e = rowptrV[v + 1];
    float d = (float)(e - b);
    invSqrtD[v] = 1.0f / sqrtf(d);
    float r = 0.0f;
    for (int j = b; j < e; ++j) r += invDE[colE[j]];
    rv[v] = r;   // r_v = sum_{e ∋ v} 1/DE_e  (data-independent phi weight)
  }
}

// ------------------------------------------------------------- phi0: B0 = X*invSqrtD, phi partial
__global__ __launch_bounds__(256) void phi0_kernel(const float* __restrict__ X,
                                                   const float* __restrict__ invSqrtD,
                                                   const float* __restrict__ rv,
                                                   float* __restrict__ B,
                                                   float* __restrict__ slot0) {
  __shared__ float red[4];
  int w = threadIdx.x >> 6;
  int v = (blockIdx.x << 2) + w;
  v = __builtin_amdgcn_readfirstlane(v);
  int lane = threadIdx.x & 63;
  float isd = invSqrtD[v];
  float2 xv = *(const float2*)(X + (size_t)v * DF + lane * 2);
  float bx = xv.x * isd, by = xv.y * isd;
  float2 o; o.x = bx; o.y = by;
  *(float2*)(B + (size_t)v * DF + lane * 2) = o;
  float q = bx * bx + by * by;
#pragma unroll
  for (int off = 32; off > 0; off >>= 1) q += __shfl_down(q, off, 64);
  if (lane == 0) red[w] = q * rv[v];
  __syncthreads();
  if (threadIdx.x == 0)
    atomicAdd(&slot0[blockIdx.x & 63], red[0] + red[1] + red[2] + red[3]);
}

// ------------------------------------------------------------- V2E pass
// one wave per hyperedge; Pe[e,d] = sqrt( invDE_e * sum_{v in e} B[v,d]^2 )
// member indices loaded with ONE coalesced load then shfl-broadcast -> no latency chain
__global__ __launch_bounds__(256) void v2e_kernel(const float* __restrict__ B, float* __restrict__ Pe,
                                                  const int* __restrict__ rowptrE,
                                                  const int* __restrict__ colV,
                                                  const float* __restrict__ invDE) {
  int e = (blockIdx.x << 2) + (threadIdx.x >> 6);
  e = __builtin_amdgcn_readfirstlane(e);
  int lane = threadIdx.x & 63;
  int beg = rowptrE[e], end = rowptrE[e + 1];
  int cnt = end - beg;
  float ax = 0.f, ay = 0.f, ax2 = 0.f, ay2 = 0.f;
  for (int c0 = 0; c0 < cnt; c0 += 64) {
    int nrem = cnt - c0;
    int nch = nrem < 64 ? nrem : 64;
    int vidx = colV[beg + c0 + (lane < nrem ? lane : nrem - 1)];
    int j = 0;
    for (; j + 4 <= nch; j += 4) {
      int v0 = __shfl(vidx, j, 64);
      int v1 = __shfl(vidx, j + 1, 64);
      int v2 = __shfl(vidx, j + 2, 64);
      int v3 = __shfl(vidx, j + 3, 64);
      float2 q0 = *(const float2*)(B + (size_t)v0 * DF + lane * 2);
      float2 q1 = *(const float2*)(B + (size_t)v1 * DF + lane * 2);
      float2 q2 = *(const float2*)(B + (size_t)v2 * DF + lane * 2);
      float2 q3 = *(const float2*)(B + (size_t)v3 * DF + lane * 2);
      ax += q0.x * q0.x + q1.x * q1.x;
      ay += q0.y * q0.y + q1.y * q1.y;
      ax2 += q2.x * q2.x + q3.x * q3.x;
      ay2 += q2.y * q2.y + q3.y * q3.y;
    }
    for (; j < nch; ++j) {
      int v0 = __shfl(vidx, j, 64);
      float2 q0 = *(const float2*)(B + (size_t)v0 * DF + lane * 2);
      ax += q0.x * q0.x;
      ay += q0.y * q0.y;
    }
  }
  ax += ax2; ay += ay2;
  float de = invDE[e];
  float2 o;
  o.x = sqrtf(ax * de);
  o.y = sqrtf(ay * de);
  *(float2*)(Pe + (size_t)e * DF + lane * 2) = o;
}

// ------------------------------------------------------------- E2V + G + phi partials
// t_v = sum_{e ∋ v} Pe[e];  G = 0.9*s_prev*t*invSqrtD + 0.1*s0*X;  store B=G*invSqrtD (or G on last)
__global__ __launch_bounds__(256) void e2v_kernel(const float* __restrict__ Pe, const float* __restrict__ X,
                                                  float* __restrict__ Bout,
                                                  const int* __restrict__ rowptrV,
                                                  const int* __restrict__ colE,
                                                  const float* __restrict__ invSqrtD,
                                                  const float* __restrict__ rv,
                                                  const float* __restrict__ slot0,
                                                  const float* __restrict__ slotPrev,
                                                  float* __restrict__ slotOut,
                                                  int isLast) {
  __shared__ float red[4];
  int w = threadIdx.x >> 6;
  int v = (blockIdx.x << 2) + w;
  v = __builtin_amdgcn_readfirstlane(v);
  int lane = threadIdx.x & 63;

  // reduce the 64 striped phi-partial slots (replaces the finalize kernel)
  float p0 = slot0[lane];
  float pp = slotPrev[lane];
#pragma unroll
  for (int off = 32; off > 0; off >>= 1) {
    p0 += __shfl_xor(p0, off, 64);
    pp += __shfl_xor(pp, off, 64);
  }
  float s0 = 1.0f / (2.0f * sqrtf(p0));
  float sp = 1.0f / (2.0f * sqrtf(pp));

  int beg = rowptrV[v], end = rowptrV[v + 1];
  int cnt = end - beg;
  float tx = 0.f, ty = 0.f, tx2 = 0.f, ty2 = 0.f;
  for (int c0 = 0; c0 < cnt; c0 += 64) {
    int nrem = cnt - c0;
    int nch = nrem < 64 ? nrem : 64;
    int eidx = colE[beg + c0 + (lane < nrem ? lane : nrem - 1)];
    int j = 0;
    for (; j + 4 <= nch; j += 4) {
      int e0 = __shfl(eidx, j, 64);
      int e1 = __shfl(eidx, j + 1, 64);
      int e2 = __shfl(eidx, j + 2, 64);
      int e3 = __shfl(eidx, j + 3, 64);
      float2 q0 = *(const float2*)(Pe + (size_t)e0 * DF + lane * 2);
      float2 q1 = *(const float2*)(Pe + (size_t)e1 * DF + lane * 2);
      float2 q2 = *(const float2*)(Pe + (size_t)e2 * DF + lane * 2);
      float2 q3 = *(const float2*)(Pe + (size_t)e3 * DF + lane * 2);
      tx += q0.x + q1.x;  ty += q0.y + q1.y;
      tx2 += q2.x + q3.x; ty2 += q2.y + q3.y;
    }
    for (; j < nch; ++j) {
      int e0 = __shfl(eidx, j, 64);
      float2 q0 = *(const float2*)(Pe + (size_t)e0 * DF + lane * 2);
      tx += q0.x; ty += q0.y;
    }
  }
  tx += tx2; ty += ty2;
  float isd = invSqrtD[v];
  float c1 = 0.9f * sp * isd;
  float c0w = 0.1f * s0;
  float2 xv = *(const float2*)(X + (size_t)v * DF + lane * 2);
  float gx = c1 * tx + c0w * xv.x;
  float gy = c1 * ty + c0w * xv.y;
  float bx = gx * isd, by = gy * isd;
  float2 o;
  if (isLast) { o.x = gx; o.y = gy; } else { o.x = bx; o.y = by; }
  *(float2*)(Bout + (size_t)v * DF + lane * 2) = o;
  float q = bx * bx + by * by;
#pragma unroll
  for (int off = 32; off > 0; off >>= 1) q += __shfl_down(q, off, 64);
  if (lane == 0) red[w] = q * rv[v];
  __syncthreads();
  if (threadIdx.x == 0)
    atomicAdd(&slotOut[blockIdx.x & 63], red[0] + red[1] + red[2] + red[3]);
}

// ------------------------------------------------------------- fused decoder
// per block: 64 nodes. GEMM1 (128->256) f32 reg-tiled + LayerNorm + ReLU + GEMM2 (256->40)
// LDS = 32 KB (Ftile aliased with hch[64][68] + per-chunk W2[64][40]) -> 4 blocks/CU
__global__ __launch_bounds__(256) void decoder_kernel(const float* __restrict__ G,
                                                      const float* __restrict__ slot10,
                                                      const float* __restrict__ W1, const float* __restrict__ b1,
                                                      const float* __restrict__ gam, const float* __restrict__ bet,
                                                      const float* __restrict__ W2, const float* __restrict__ b2,
                                                      float* __restrict__ out) {
  __shared__ float smem[8192];            // 32,768 B
  float* Ft = smem;
  const int tid = threadIdx.x;
  const int lane = tid & 63;
  const int node0 = blockIdx.x * 64;

  float ps = slot10[lane];
#pragma unroll
  for (int off = 32; off > 0; off >>= 1) ps += __shfl_xor(ps, off, 64);
  const float s = 1.0f / (2.0f * sqrtf(ps));   // s10 = 1/phi(G10)

  // stage F tile = s * G rows (zero-pad OOB nodes)
  const float4* Gv = (const float4*)(G + (size_t)node0 * DF);
  for (int i = tid; i < 2048; i += 256) {
    int nd = i >> 5;                       // 32 float4 per row
    float4 f;
    if (node0 + nd < N_NODES) f = Gv[i];
    else f = make_float4(0.f, 0.f, 0.f, 0.f);
    f.x *= s; f.y *= s; f.z *= s; f.w *= s;
    ((float4*)Ft)[i] = f;
  }
  __syncthreads();

  const int rt = tid >> 5;                 // 0..7  -> node group of 8
  const int ct = tid & 31;                 // 0..31 -> hid group of 8
  float bias[8], g8[8], be8[8];
#pragma unroll
  for (int j = 0; j < 8; ++j) {
    bias[j] = b1[ct * 8 + j];
    g8[j] = gam[ct * 8 + j];
    be8[j] = bet[ct * 8 + j];
  }
  float acc[8][8];
#pragma unroll
  for (int i = 0; i < 8; ++i)
#pragma unroll
    for (int j = 0; j < 8; ++j) acc[i][j] = bias[j];

  for (int k4 = 0; k4 < 32; ++k4) {
    float4 a4[8];
#pragma unroll
    for (int i = 0; i < 8; ++i) a4[i] = *(const float4*)(&Ft[(rt * 8 + i) * 128 + k4 * 4]);
#pragma unroll
    for (int kk = 0; kk < 4; ++kk) {
      const float* wrow = W1 + (k4 * 4 + kk) * HID + ct * 8;
      float4 b0 = *(const float4*)(wrow);
      float4 b1v = *(const float4*)(wrow + 4);
      float bb[8] = {b0.x, b0.y, b0.z, b0.w, b1v.x, b1v.y, b1v.z, b1v.w};
#pragma unroll
      for (int i = 0; i < 8; ++i) {
        float av = (kk == 0) ? a4[i].x : (kk == 1) ? a4[i].y : (kk == 2) ? a4[i].z : a4[i].w;
#pragma unroll
        for (int j = 0; j < 8; ++j) acc[i][j] += av * bb[j];
      }
    }
  }

  // LayerNorm over 256 hid dims (32 lanes of same rt hold the row) + ReLU
#pragma unroll
  for (int i = 0; i < 8; ++i) {
    float s1 = 0.f, s2 = 0.f;
#pragma unroll
    for (int j = 0; j < 8; ++j) { s1 += acc[i][j]; s2 += acc[i][j] * acc[i][j]; }
#pragma unroll
    for (int off = 16; off > 0; off >>= 1) {
      s1 += __shfl_xor(s1, off, 64);
      s2 += __shfl_xor(s2, off, 64);
    }
    float mu = s1 * (1.0f / 256.0f);
    float var = s2 * (1.0f / 256.0f) - mu * mu;
    float rs = rsqrtf(var + 1e-5f);
#pragma unroll
    for (int j = 0; j < 8; ++j)
      acc[i][j] = fmaxf(0.0f, (acc[i][j] - mu) * rs * g8[j] + be8[j]);
  }
  __syncthreads();   // Ftile dead from here

  float* hch = smem;                       // [64][68] padded chunk of h = 17,408 B
  float* W2c = smem + 64 * 68;             // [64][40] chunk of W2 = 10,240 B

  const int n_l = tid >> 2;                // 0..63 node
  const int og = tid & 3;                  // 4 groups of 10 outputs
  float oacc[10];
#pragma unroll
  for (int j = 0; j < 10; ++j) oacc[j] = b2[og * 10 + j];

  for (int c = 0; c < 4; ++c) {            // 4 chunks of 64 hid dims
    for (int i = tid; i < 64 * NOUT; i += 256) W2c[i] = W2[c * 64 * NOUT + i];
    if ((ct >> 3) == c) {
      int c8 = (ct & 7) * 8;
#pragma unroll
      for (int i = 0; i < 8; ++i)
#pragma unroll
        for (int j = 0; j < 8; ++j) hch[(rt * 8 + i) * 68 + c8 + j] = acc[i][j];
    }
    __syncthreads();
    for (int kk = 0; kk < 64; ++kk) {
      float hv = hch[n_l * 68 + kk];
      const float* w = W2c + kk * NOUT + og * 10;
#pragma unroll
      for (int j = 0; j < 10; ++j) oacc[j] += hv * w[j];
    }
    __syncthreads();
  }

  int node = node0 + n_l;
  if (node < N_NODES) {
#pragma unroll
    for (int j = 0; j < 10; ++j) out[(size_t)node * NOUT + og * 10 + j] = oacc[j];
  }
}

// ---------------------------------------------------------------- launch
extern "C" void kernel_launch(void* const* d_in, const int* in_sizes, int n_in,
                              void* d_out, int out_size, void* d_ws, size_t ws_size,
                              hipStream_t stream) {
  (void)in_sizes; (void)n_in; (void)out_size; (void)ws_size;
  const float* x = (const float*)d_in[0];
  const int* he = (const int*)d_in[1];
  const int* V = he;
  const int* E = he + NNZ_TOT;
  const float* W1 = (const float*)d_in[2];
  const float* b1 = (const float*)d_in[3];
  const float* gam = (const float*)d_in[4];
  const float* bet = (const float*)d_in[5];
  const float* W2 = (const float*)d_in[6];
  const float* b2 = (const float*)d_in[7];
  float* out = (float*)d_out;

  // Pe (5.12 MB) lives in d_out (8 MB): dead before decoder (sole d_out writer) runs.
  float* Pe = (float*)d_out;

  char* p = (char*)d_ws;
  auto nextp = [&](size_t bytes) -> char* {
    char* r = p;
    p += (bytes + 255) & ~(size_t)255;
    return r;
  };
  // cnt arrays + 11x64 phi slots contiguous -> one memset covers all
  int* cntV      = (int*)nextp((size_t)(N_NODES + M_EDGES) * 4 + 11 * 64 * 4);
  int* cntE      = cntV + N_NODES;
  float* phis    = (float*)(cntE + M_EDGES);     // [11][64] striped phi partials
  int* rowptrV   = (int*)nextp((size_t)(N_NODES + 1) * 4);
  int* rowptrE   = (int*)nextp((size_t)(M_EDGES + 1) * 4);
  int* colE      = (int*)nextp((size_t)NNZ_TOT * 4);
  int* colV      = (int*)nextp((size_t)NNZ_TOT * 4);
  float* invSqrtD= (float*)nextp((size_t)N_NODES * 4);
  float* rv      = (float*)nextp((size_t)N_NODES * 4);
  float* invDE   = (float*)nextp((size_t)M_EDGES * 4);
  float* B       = (float*)nextp((size_t)N_NODES * DF * 4);
  // total ~29.5 MiB

  const int NBLK_NNZ = (NNZ_TOT + 255) / 256;

  hipMemsetAsync(cntV, 0, (size_t)(N_NODES + M_EDGES) * 4 + 11 * 64 * 4, stream);
  count_kernel<<<NBLK_NNZ, 256, 0, stream>>>(V, E, cntV, cntE);
  scan_kernel<<<1, 1024, 0, stream>>>(cntV, N_NODES, rowptrV);
  scan_kernel<<<1, 1024, 0, stream>>>(cntE, M_EDGES, rowptrE);
  fill_kernel<<<NBLK_NNZ, 256, 0, stream>>>(V, E, cntV, cntE, colE, colV);
  edge_stats_kernel<<<(M_EDGES + 255) / 256, 256, 0, stream>>>(rowptrE, invDE);
  node_stats_kernel<<<(N_NODES + 255) / 256, 256, 0, stream>>>(rowptrV, colE, invDE, invSqrtD, rv);
  phi0_kernel<<<N_NODES / 4, 256, 0, stream>>>(x, invSqrtD, rv, B, phis);

  for (int k = 1; k <= 10; ++k) {
    v2e_kernel<<<M_EDGES / 4, 256, 0, stream>>>(B, Pe, rowptrE, colV, invDE);
    e2v_kernel<<<N_NODES / 4, 256, 0, stream>>>(Pe, x, B, rowptrV, colE, invSqrtD, rv,
                                                phis, phis + (size_t)(k - 1) * 64,
                                                phis + (size_t)k * 64, (k == 10) ? 1 : 0);
  }

  decoder_kernel<<<(N_NODES + 63) / 64, 256, 0, stream>>>(B, phis + 640, W1, b1, gam, bet, W2, b2, out);
}

// Round 4
// 1075.208 us; speedup vs baseline: 1.1677x; 1.1588x over previous
//
#include <hip/hip_runtime.h>
#include <hip/hip_fp16.h>

#define N_NODES 50000
#define M_EDGES 10000
#define NNZ_TOT 400000
#define DF      128
#define HID     256
#define NOUT    40

// ---------------------------------------------------------------- CSR build
__global__ __launch_bounds__(256) void count_kernel(const int* __restrict__ V, const int* __restrict__ E,
                                                    int* __restrict__ cntV, int* __restrict__ cntE) {
  int i = blockIdx.x * 256 + threadIdx.x;
  if (i < NNZ_TOT) {
    int v = V[i]; v = (v < 0) ? 0 : (v >= N_NODES ? N_NODES - 1 : v);
    int e = E[i]; e = (e < 0) ? 0 : (e >= M_EDGES ? M_EDGES - 1 : e);
    atomicAdd(&cntV[v], 1);
    atomicAdd(&cntE[e], 1);
  }
}

// single-block exclusive scan; writes rowptr[0..n]; converts cnt[] in place into
// the running cursor array for the fill pass (alias-safe: thread-local temp).
__global__ __launch_bounds__(1024) void scan_kernel(int* __restrict__ cnt, int n,
                                                    int* __restrict__ rowptr) {
  __shared__ int sm[1024];
  int chunk = (n + 1023) >> 10;
  int beg = threadIdx.x * chunk;
  int end = beg + chunk;
  if (beg > n) beg = n;
  if (end > n) end = n;
  int s = 0;
  for (int i = beg; i < end; ++i) s += cnt[i];
  sm[threadIdx.x] = s;
  __syncthreads();
  for (int off = 1; off < 1024; off <<= 1) {
    int t = (threadIdx.x >= (unsigned)off) ? sm[threadIdx.x - off] : 0;
    __syncthreads();
    sm[threadIdx.x] += t;
    __syncthreads();
  }
  int run = sm[threadIdx.x] - s;
  for (int i = beg; i < end; ++i) {
    int c = cnt[i];                // read BEFORE overwrite (cnt doubles as cursor)
    rowptr[i] = run;
    cnt[i] = run;
    run += c;
  }
  if (threadIdx.x == 1023) rowptr[n] = sm[1023];
}

__global__ __launch_bounds__(256) void fill_kernel(const int* __restrict__ V, const int* __restrict__ E,
                                                   int* __restrict__ curV, int* __restrict__ curE,
                                                   int* __restrict__ colE, int* __restrict__ colV) {
  int i = blockIdx.x * 256 + threadIdx.x;
  if (i < NNZ_TOT) {
    int v = V[i]; v = (v < 0) ? 0 : (v >= N_NODES ? N_NODES - 1 : v);
    int e = E[i]; e = (e < 0) ? 0 : (e >= M_EDGES ? M_EDGES - 1 : e);
    int p = atomicAdd(&curV[v], 1);
    colE[p] = e;                    // edges grouped by node
    int q = atomicAdd(&curE[e], 1);
    colV[q] = v;                    // nodes grouped by edge
  }
}

__global__ __launch_bounds__(256) void edge_stats_kernel(const int* __restrict__ rowptrE,
                                                         float* __restrict__ invDE) {
  int e = blockIdx.x * 256 + threadIdx.x;
  if (e < M_EDGES) invDE[e] = 1.0f / (float)(rowptrE[e + 1] - rowptrE[e]);
}

__global__ __launch_bounds__(256) void node_stats_kernel(const int* __restrict__ rowptrV,
                                                         const int* __restrict__ colE,
                                                         const float* __restrict__ invDE,
                                                         float* __restrict__ invSqrtD,
                                                         float* __restrict__ rv) {
  int v = blockIdx.x * 256 + threadIdx.x;
  if (v < N_NODES) {
    int b = rowptrV[v], e = rowptrV[v + 1];
    float d = (float)(e - b);
    invSqrtD[v] = 1.0f / sqrtf(d);
    float r = 0.0f;
    for (int j = b; j < e; ++j) r += invDE[colE[j]];
    rv[v] = r;   // r_v = sum_{e ∋ v} 1/DE_e  (data-independent phi weight)
  }
}

// ------------------------------------------------------------- phi0: Bh0 = fp16(X*invSqrtD), phi partial
__global__ __launch_bounds__(256) void phi0_kernel(const float* __restrict__ X,
                                                   const float* __restrict__ invSqrtD,
                                                   const float* __restrict__ rv,
                                                   __half2* __restrict__ Bh,
                                                   float* __restrict__ slot0) {
  __shared__ float red[4];
  int w = threadIdx.x >> 6;
  int v = (blockIdx.x << 2) + w;
  v = __builtin_amdgcn_readfirstlane(v);
  int lane = threadIdx.x & 63;
  float isd = invSqrtD[v];
  float2 xv = *(const float2*)(X + (size_t)v * DF + lane * 2);
  float bx = xv.x * isd, by = xv.y * isd;
  Bh[(size_t)v * 64 + lane] = __floats2half2_rn(bx, by);
  float q = bx * bx + by * by;
#pragma unroll
  for (int off = 32; off > 0; off >>= 1) q += __shfl_down(q, off, 64);
  if (lane == 0) red[w] = q * rv[v];
  __syncthreads();
  if (threadIdx.x == 0)
    atomicAdd(&slot0[blockIdx.x & 63], red[0] + red[1] + red[2] + red[3]);
}

// ------------------------------------------------------------- V2E pass
// one wave per hyperedge; Pe[e,d] = sqrt( invDE_e * sum_{v in e} B[v,d]^2 )   (fp16 gather)
__global__ __launch_bounds__(256) void v2e_kernel(const __half2* __restrict__ Bh, __half2* __restrict__ Peh,
                                                  const int* __restrict__ rowptrE,
                                                  const int* __restrict__ colV,
                                                  const float* __restrict__ invDE) {
  int e = (blockIdx.x << 2) + (threadIdx.x >> 6);
  e = __builtin_amdgcn_readfirstlane(e);
  int lane = threadIdx.x & 63;
  int beg = rowptrE[e], end = rowptrE[e + 1];
  int cnt = end - beg;
  float ax = 0.f, ay = 0.f, ax2 = 0.f, ay2 = 0.f;
  for (int c0 = 0; c0 < cnt; c0 += 64) {
    int nrem = cnt - c0;
    int nch = nrem < 64 ? nrem : 64;
    int vidx = colV[beg + c0 + (lane < nrem ? lane : nrem - 1)];
    int j = 0;
    for (; j + 8 <= nch; j += 8) {
      int v0 = __shfl(vidx, j, 64),     v1 = __shfl(vidx, j + 1, 64);
      int v2 = __shfl(vidx, j + 2, 64), v3 = __shfl(vidx, j + 3, 64);
      int v4 = __shfl(vidx, j + 4, 64), v5 = __shfl(vidx, j + 5, 64);
      int v6 = __shfl(vidx, j + 6, 64), v7 = __shfl(vidx, j + 7, 64);
      float2 q0 = __half22float2(Bh[(size_t)v0 * 64 + lane]);
      float2 q1 = __half22float2(Bh[(size_t)v1 * 64 + lane]);
      float2 q2 = __half22float2(Bh[(size_t)v2 * 64 + lane]);
      float2 q3 = __half22float2(Bh[(size_t)v3 * 64 + lane]);
      float2 q4 = __half22float2(Bh[(size_t)v4 * 64 + lane]);
      float2 q5 = __half22float2(Bh[(size_t)v5 * 64 + lane]);
      float2 q6 = __half22float2(Bh[(size_t)v6 * 64 + lane]);
      float2 q7 = __half22float2(Bh[(size_t)v7 * 64 + lane]);
      ax  += q0.x * q0.x + q1.x * q1.x + q4.x * q4.x + q5.x * q5.x;
      ay  += q0.y * q0.y + q1.y * q1.y + q4.y * q4.y + q5.y * q5.y;
      ax2 += q2.x * q2.x + q3.x * q3.x + q6.x * q6.x + q7.x * q7.x;
      ay2 += q2.y * q2.y + q3.y * q3.y + q6.y * q6.y + q7.y * q7.y;
    }
    for (; j < nch; ++j) {
      int v0 = __shfl(vidx, j, 64);
      float2 q0 = __half22float2(Bh[(size_t)v0 * 64 + lane]);
      ax += q0.x * q0.x;
      ay += q0.y * q0.y;
    }
  }
  ax += ax2; ay += ay2;
  float de = invDE[e];
  Peh[(size_t)e * 64 + lane] = __floats2half2_rn(sqrtf(ax * de), sqrtf(ay * de));
}

// ------------------------------------------------------------- E2V + G + phi partials
// t_v = sum_{e ∋ v} Pe[e];  G = 0.9*sp*t*invSqrtD + 0.1*s0*X;
// store Bh = fp16(G*invSqrtD)  (or fp16(G) on last iteration, for the decoder)
__global__ __launch_bounds__(256) void e2v_kernel(const __half2* __restrict__ Peh, const float* __restrict__ X,
                                                  __half2* __restrict__ Bh,
                                                  const int* __restrict__ rowptrV,
                                                  const int* __restrict__ colE,
                                                  const float* __restrict__ invSqrtD,
                                                  const float* __restrict__ rv,
                                                  const float* __restrict__ slot0,
                                                  const float* __restrict__ slotPrev,
                                                  float* __restrict__ slotOut,
                                                  int isLast) {
  __shared__ float red[4];
  int w = threadIdx.x >> 6;
  int v = (blockIdx.x << 2) + w;
  v = __builtin_amdgcn_readfirstlane(v);
  int lane = threadIdx.x & 63;

  // reduce the 64 striped phi-partial slots (replaces a finalize kernel)
  float p0 = slot0[lane];
  float pp = slotPrev[lane];
#pragma unroll
  for (int off = 32; off > 0; off >>= 1) {
    p0 += __shfl_xor(p0, off, 64);
    pp += __shfl_xor(pp, off, 64);
  }
  float s0 = 1.0f / (2.0f * sqrtf(p0));
  float sp = 1.0f / (2.0f * sqrtf(pp));

  int beg = rowptrV[v], end = rowptrV[v + 1];
  int cnt = end - beg;
  float tx = 0.f, ty = 0.f, tx2 = 0.f, ty2 = 0.f;
  for (int c0 = 0; c0 < cnt; c0 += 64) {
    int nrem = cnt - c0;
    int nch = nrem < 64 ? nrem : 64;
    int eidx = colE[beg + c0 + (lane < nrem ? lane : nrem - 1)];
    int j = 0;
    for (; j + 8 <= nch; j += 8) {
      int e0 = __shfl(eidx, j, 64),     e1 = __shfl(eidx, j + 1, 64);
      int e2 = __shfl(eidx, j + 2, 64), e3 = __shfl(eidx, j + 3, 64);
      int e4 = __shfl(eidx, j + 4, 64), e5 = __shfl(eidx, j + 5, 64);
      int e6 = __shfl(eidx, j + 6, 64), e7 = __shfl(eidx, j + 7, 64);
      float2 q0 = __half22float2(Peh[(size_t)e0 * 64 + lane]);
      float2 q1 = __half22float2(Peh[(size_t)e1 * 64 + lane]);
      float2 q2 = __half22float2(Peh[(size_t)e2 * 64 + lane]);
      float2 q3 = __half22float2(Peh[(size_t)e3 * 64 + lane]);
      float2 q4 = __half22float2(Peh[(size_t)e4 * 64 + lane]);
      float2 q5 = __half22float2(Peh[(size_t)e5 * 64 + lane]);
      float2 q6 = __half22float2(Peh[(size_t)e6 * 64 + lane]);
      float2 q7 = __half22float2(Peh[(size_t)e7 * 64 + lane]);
      tx  += q0.x + q1.x + q4.x + q5.x;
      ty  += q0.y + q1.y + q4.y + q5.y;
      tx2 += q2.x + q3.x + q6.x + q7.x;
      ty2 += q2.y + q3.y + q6.y + q7.y;
    }
    for (; j < nch; ++j) {
      int e0 = __shfl(eidx, j, 64);
      float2 q0 = __half22float2(Peh[(size_t)e0 * 64 + lane]);
      tx += q0.x; ty += q0.y;
    }
  }
  tx += tx2; ty += ty2;
  float isd = invSqrtD[v];
  float c1 = 0.9f * sp * isd;
  float c0w = 0.1f * s0;
  float2 xv = *(const float2*)(X + (size_t)v * DF + lane * 2);
  float gx = c1 * tx + c0w * xv.x;
  float gy = c1 * ty + c0w * xv.y;
  float bx = gx * isd, by = gy * isd;
  Bh[(size_t)v * 64 + lane] = isLast ? __floats2half2_rn(gx, gy) : __floats2half2_rn(bx, by);
  float q = bx * bx + by * by;
#pragma unroll
  for (int off = 32; off > 0; off >>= 1) q += __shfl_down(q, off, 64);
  if (lane == 0) red[w] = q * rv[v];
  __syncthreads();
  if (threadIdx.x == 0)
    atomicAdd(&slotOut[blockIdx.x & 63], red[0] + red[1] + red[2] + red[3]);
}

// ------------------------------------------------------------- fused decoder
// 512 threads (8 waves), 64 nodes/block. GEMM1 (128->256) f32 reg-tiled + LN + ReLU + GEMM2 (256->40)
// LDS = 32 KB (Ftile aliased with hch[64][68] + per-chunk W2[64][40])
__global__ __launch_bounds__(512) void decoder_kernel(const __half2* __restrict__ Gh,
                                                      const float* __restrict__ slot10,
                                                      const float* __restrict__ W1, const float* __restrict__ b1,
                                                      const float* __restrict__ gam, const float* __restrict__ bet,
                                                      const float* __restrict__ W2, const float* __restrict__ b2,
                                                      float* __restrict__ out) {
  __shared__ float smem[8192];            // 32,768 B
  float* Ft = smem;
  const int tid = threadIdx.x;
  const int lane = tid & 63;
  const int node0 = blockIdx.x * 64;

  float ps = slot10[lane];
#pragma unroll
  for (int off = 32; off > 0; off >>= 1) ps += __shfl_xor(ps, off, 64);
  const float s = 1.0f / (2.0f * sqrtf(ps));   // s10 = 1/phi(G10)

  // stage F tile = s * G rows (fp16 source; zero-pad OOB nodes)
  for (int i = tid; i < 4096; i += 512) {       // 64 rows x 64 half2
    int nd = i >> 6, c2 = i & 63;
    float2 f = make_float2(0.f, 0.f);
    if (node0 + nd < N_NODES) {
      float2 g = __half22float2(Gh[((size_t)(node0 + nd)) * 64 + c2]);
      f.x = g.x * s; f.y = g.y * s;
    }
    *(float2*)(&Ft[nd * 128 + c2 * 2]) = f;
  }
  __syncthreads();

  const int rt = tid >> 5;                 // 0..15 -> node group of 4
  const int ct = tid & 31;                 // 0..31 -> hid group of 8
  float bias[8], g8[8], be8[8];
#pragma unroll
  for (int j = 0; j < 8; ++j) {
    bias[j] = b1[ct * 8 + j];
    g8[j] = gam[ct * 8 + j];
    be8[j] = bet[ct * 8 + j];
  }
  float acc[4][8];
#pragma unroll
  for (int i = 0; i < 4; ++i)
#pragma unroll
    for (int j = 0; j < 8; ++j) acc[i][j] = bias[j];

  for (int k4 = 0; k4 < 32; ++k4) {
    float4 a4[4];
#pragma unroll
    for (int i = 0; i < 4; ++i) a4[i] = *(const float4*)(&Ft[(rt * 4 + i) * 128 + k4 * 4]);
#pragma unroll
    for (int kk = 0; kk < 4; ++kk) {
      const float* wrow = W1 + (k4 * 4 + kk) * HID + ct * 8;
      float4 b0 = *(const float4*)(wrow);
      float4 b1v = *(const float4*)(wrow + 4);
      float bb[8] = {b0.x, b0.y, b0.z, b0.w, b1v.x, b1v.y, b1v.z, b1v.w};
#pragma unroll
      for (int i = 0; i < 4; ++i) {
        float av = (kk == 0) ? a4[i].x : (kk == 1) ? a4[i].y : (kk == 2) ? a4[i].z : a4[i].w;
#pragma unroll
        for (int j = 0; j < 8; ++j) acc[i][j] += av * bb[j];
      }
    }
  }

  // LayerNorm over 256 hid dims (the 32 lanes sharing rt hold one row) + ReLU
#pragma unroll
  for (int i = 0; i < 4; ++i) {
    float s1 = 0.f, s2 = 0.f;
#pragma unroll
    for (int j = 0; j < 8; ++j) { s1 += acc[i][j]; s2 += acc[i][j] * acc[i][j]; }
#pragma unroll
    for (int off = 16; off > 0; off >>= 1) {      // xor<32 stays within the rt half-wave
      s1 += __shfl_xor(s1, off, 64);
      s2 += __shfl_xor(s2, off, 64);
    }
    float mu = s1 * (1.0f / 256.0f);
    float var = s2 * (1.0f / 256.0f) - mu * mu;
    float rs = rsqrtf(var + 1e-5f);
#pragma unroll
    for (int j = 0; j < 8; ++j)
      acc[i][j] = fmaxf(0.0f, (acc[i][j] - mu) * rs * g8[j] + be8[j]);
  }
  __syncthreads();   // Ftile dead from here

  float* hch = smem;                       // [64][68] padded chunk of h = 17,408 B
  float* W2c = smem + 64 * 68;             // [64][40] chunk of W2 = 10,240 B

  const int n_l = tid >> 3;                // 0..63 node
  const int og = tid & 7;                  // 8 groups of 5 outputs
  float oacc[5];
#pragma unroll
  for (int j = 0; j < 5; ++j) oacc[j] = b2[og * 5 + j];

  for (int c = 0; c < 4; ++c) {            // 4 chunks of 64 hid dims
    for (int i = tid; i < 64 * NOUT; i += 512) W2c[i] = W2[c * 64 * NOUT + i];
    if ((ct >> 3) == c) {
      int c8 = (ct & 7) * 8;
#pragma unroll
      for (int i = 0; i < 4; ++i)
#pragma unroll
        for (int j = 0; j < 8; ++j) hch[(rt * 4 + i) * 68 + c8 + j] = acc[i][j];
    }
    __syncthreads();
    for (int kk = 0; kk < 64; ++kk) {
      float hv = hch[n_l * 68 + kk];
      const float* wp = W2c + kk * NOUT + og * 5;
#pragma unroll
      for (int j = 0; j < 5; ++j) oacc[j] += hv * wp[j];
    }
    __syncthreads();
  }

  int node = node0 + n_l;
  if (node < N_NODES) {
#pragma unroll
    for (int j = 0; j < 5; ++j) out[(size_t)node * NOUT + og * 5 + j] = oacc[j];
  }
}

// ---------------------------------------------------------------- launch
extern "C" void kernel_launch(void* const* d_in, const int* in_sizes, int n_in,
                              void* d_out, int out_size, void* d_ws, size_t ws_size,
                              hipStream_t stream) {
  (void)in_sizes; (void)n_in; (void)out_size; (void)ws_size;
  const float* x = (const float*)d_in[0];
  const int* he = (const int*)d_in[1];
  const int* V = he;
  const int* E = he + NNZ_TOT;
  const float* W1 = (const float*)d_in[2];
  const float* b1 = (const float*)d_in[3];
  const float* gam = (const float*)d_in[4];
  const float* bet = (const float*)d_in[5];
  const float* W2 = (const float*)d_in[6];
  const float* b2 = (const float*)d_in[7];
  float* out = (float*)d_out;

  // Peh (2.56 MB fp16) lives in d_out (8 MB): dead before decoder (sole d_out writer) runs.
  __half2* Peh = (__half2*)d_out;

  char* p = (char*)d_ws;
  auto nextp = [&](size_t bytes) -> char* {
    char* r = p;
    p += (bytes + 255) & ~(size_t)255;
    return r;
  };
  // cnt arrays + 11x64 phi slots contiguous -> one memset covers all
  int* cntV      = (int*)nextp((size_t)(N_NODES + M_EDGES) * 4 + 11 * 64 * 4);
  int* cntE      = cntV + N_NODES;
  float* phis    = (float*)(cntE + M_EDGES);     // [11][64] striped phi partials
  int* rowptrV   = (int*)nextp((size_t)(N_NODES + 1) * 4);
  int* rowptrE   = (int*)nextp((size_t)(M_EDGES + 1) * 4);
  int* colE      = (int*)nextp((size_t)NNZ_TOT * 4);
  int* colV      = (int*)nextp((size_t)NNZ_TOT * 4);
  float* invSqrtD= (float*)nextp((size_t)N_NODES * 4);
  float* rv      = (float*)nextp((size_t)N_NODES * 4);
  float* invDE   = (float*)nextp((size_t)M_EDGES * 4);
  __half2* Bh    = (__half2*)nextp((size_t)N_NODES * DF * 2);   // fp16 iterate, 12.8 MB
  // total ~17 MiB

  const int NBLK_NNZ = (NNZ_TOT + 255) / 256;

  hipMemsetAsync(cntV, 0, (size_t)(N_NODES + M_EDGES) * 4 + 11 * 64 * 4, stream);
  count_kernel<<<NBLK_NNZ, 256, 0, stream>>>(V, E, cntV, cntE);
  scan_kernel<<<1, 1024, 0, stream>>>(cntV, N_NODES, rowptrV);
  scan_kernel<<<1, 1024, 0, stream>>>(cntE, M_EDGES, rowptrE);
  fill_kernel<<<NBLK_NNZ, 256, 0, stream>>>(V, E, cntV, cntE, colE, colV);
  edge_stats_kernel<<<(M_EDGES + 255) / 256, 256, 0, stream>>>(rowptrE, invDE);
  node_stats_kernel<<<(N_NODES + 255) / 256, 256, 0, stream>>>(rowptrV, colE, invDE, invSqrtD, rv);
  phi0_kernel<<<N_NODES / 4, 256, 0, stream>>>(x, invSqrtD, rv, Bh, phis);

  for (int k = 1; k <= 10; ++k) {
    v2e_kernel<<<M_EDGES / 4, 256, 0, stream>>>(Bh, Peh, rowptrE, colV, invDE);
    e2v_kernel<<<N_NODES / 4, 256, 0, stream>>>(Peh, x, Bh, rowptrV, colE, invSqrtD, rv,
                                                phis, phis + (size_t)(k - 1) * 64,
                                                phis + (size_t)k * 64, (k == 10) ? 1 : 0);
  }

  decoder_kernel<<<(N_NODES + 63) / 64, 512, 0, stream>>>(Bh, phis + 640, W1, b1, gam, bet, W2, b2, out);
}

// Round 5
// 842.091 us; speedup vs baseline: 1.4910x; 1.2768x over previous
//
#include <hip/hip_runtime.h>
#include <hip/hip_fp16.h>

#define N_NODES 50000
#define M_EDGES 10000
#define NNZ_TOT 400000
#define DF      128
#define HID     256
#define NOUT    40

// ---------------------------------------------------------------- CSR build
__global__ __launch_bounds__(256) void count_kernel(const int* __restrict__ V, const int* __restrict__ E,
                                                    int* __restrict__ cntV, int* __restrict__ cntE) {
  int i = blockIdx.x * 256 + threadIdx.x;
  if (i < NNZ_TOT) {
    int v = V[i]; v = (v < 0) ? 0 : (v >= N_NODES ? N_NODES - 1 : v);
    int e = E[i]; e = (e < 0) ? 0 : (e >= M_EDGES ? M_EDGES - 1 : e);
    atomicAdd(&cntV[v], 1);
    atomicAdd(&cntE[e], 1);
  }
}

// single-block exclusive scan; rowptr[0..n]; cnt[] becomes the fill cursor in place
__global__ __launch_bounds__(1024) void scan_kernel(int* __restrict__ cnt, int n,
                                                    int* __restrict__ rowptr) {
  __shared__ int sm[1024];
  int chunk = (n + 1023) >> 10;
  int beg = threadIdx.x * chunk;
  int end = beg + chunk;
  if (beg > n) beg = n;
  if (end > n) end = n;
  int s = 0;
  for (int i = beg; i < end; ++i) s += cnt[i];
  sm[threadIdx.x] = s;
  __syncthreads();
  for (int off = 1; off < 1024; off <<= 1) {
    int t = (threadIdx.x >= (unsigned)off) ? sm[threadIdx.x - off] : 0;
    __syncthreads();
    sm[threadIdx.x] += t;
    __syncthreads();
  }
  int run = sm[threadIdx.x] - s;
  for (int i = beg; i < end; ++i) {
    int c = cnt[i];
    rowptr[i] = run;
    cnt[i] = run;
    run += c;
  }
  if (threadIdx.x == 1023) rowptr[n] = sm[1023];
}

__global__ __launch_bounds__(256) void fill_kernel(const int* __restrict__ V, const int* __restrict__ E,
                                                   int* __restrict__ curV, int* __restrict__ curE,
                                                   int* __restrict__ colE, int* __restrict__ colV) {
  int i = blockIdx.x * 256 + threadIdx.x;
  if (i < NNZ_TOT) {
    int v = V[i]; v = (v < 0) ? 0 : (v >= N_NODES ? N_NODES - 1 : v);
    int e = E[i]; e = (e < 0) ? 0 : (e >= M_EDGES ? M_EDGES - 1 : e);
    int p = atomicAdd(&curV[v], 1);
    colE[p] = e;
    int q = atomicAdd(&curE[e], 1);
    colV[q] = v;
  }
}

__global__ __launch_bounds__(256) void edge_stats_kernel(const int* __restrict__ rowptrE,
                                                         float* __restrict__ invDE) {
  int e = blockIdx.x * 256 + threadIdx.x;
  if (e < M_EDGES) invDE[e] = 1.0f / (float)(rowptrE[e + 1] - rowptrE[e]);
}

__global__ __launch_bounds__(256) void node_stats_kernel(const int* __restrict__ rowptrV,
                                                         const int* __restrict__ colE,
                                                         const float* __restrict__ invDE,
                                                         float* __restrict__ invSqrtD,
                                                         float* __restrict__ rv) {
  int v = blockIdx.x * 256 + threadIdx.x;
  if (v < N_NODES) {
    int b = rowptrV[v], e = rowptrV[v + 1];
    float d = (float)(e - b);
    invSqrtD[v] = 1.0f / sqrtf(d);
    float r = 0.0f;
    for (int j = b; j < e; ++j) r += invDE[colE[j]];
    rv[v] = r;
  }
}

// ------------------------------------------------------------- phi0: Bh0 = fp16(X*invSqrtD), phi partial
__global__ __launch_bounds__(256) void phi0_kernel(const float* __restrict__ X,
                                                   const float* __restrict__ invSqrtD,
                                                   const float* __restrict__ rv,
                                                   __half2* __restrict__ Bh,
                                                   float* __restrict__ slot0) {
  __shared__ float red[4];
  int w = threadIdx.x >> 6;
  int v = (blockIdx.x << 2) + w;
  v = __builtin_amdgcn_readfirstlane(v);
  int lane = threadIdx.x & 63;
  float isd = invSqrtD[v];
  float2 xv = *(const float2*)(X + (size_t)v * DF + lane * 2);
  float bx = xv.x * isd, by = xv.y * isd;
  Bh[(size_t)v * 64 + lane] = __floats2half2_rn(bx, by);
  float q = bx * bx + by * by;
#pragma unroll
  for (int off = 32; off > 0; off >>= 1) q += __shfl_down(q, off, 64);
  if (lane == 0) red[w] = q * rv[v];
  __syncthreads();
  if (threadIdx.x == 0)
    atomicAdd(&slot0[blockIdx.x & 63], red[0] + red[1] + red[2] + red[3]);
}

// ------------------------------------------------------------- V2E pass
// 4 edges per wave (one per 16-lane group). Lane loads float4 (8 feats) of a member row:
// 16 lanes cover the 256B row; one wave-load gathers 4 rows (one per group).
__global__ __launch_bounds__(256) void v2e_kernel(const __half2* __restrict__ Bh, __half2* __restrict__ Peh,
                                                  const int* __restrict__ rowptrE,
                                                  const int* __restrict__ colV,
                                                  const float* __restrict__ invDE) {
  const int tid = threadIdx.x;
  const int lane = tid & 63;
  const int grp = lane >> 4;          // edge within wave
  const int sub = lane & 15;          // 16B feature slice within row
  const int e = blockIdx.x * 16 + (tid >> 6) * 4 + grp;   // grid 625*16 = 10000 exact
  const int beg = rowptrE[e], end = rowptrE[e + 1];
  const int cnt = end - beg;
  int cmax = cnt;
  cmax = max(cmax, __shfl_xor(cmax, 16, 64));
  cmax = max(cmax, __shfl_xor(cmax, 32, 64));

  float acc[8];
#pragma unroll
  for (int i = 0; i < 8; ++i) acc[i] = 0.f;
  const char* Bb = (const char*)Bh;

  for (int c0 = 0; c0 < cmax; c0 += 16) {
    int li = c0 + sub;
    int vidx = colV[beg + (li < cnt ? li : cnt - 1)];
#pragma unroll
    for (int half = 0; half < 2; ++half) {
      float4 r[8];
#pragma unroll
      for (int u = 0; u < 8; ++u) {
        int m = __shfl(vidx, (grp << 4) | (half * 8 + u), 64);
        r[u] = *(const float4*)(Bb + ((size_t)m << 8) + (sub << 4));
      }
#pragma unroll
      for (int u = 0; u < 8; ++u) {
        if (c0 + half * 8 + u < cnt) {
          const __half2* h = (const __half2*)&r[u];
          float2 a0 = __half22float2(h[0]);
          float2 a1 = __half22float2(h[1]);
          float2 a2 = __half22float2(h[2]);
          float2 a3 = __half22float2(h[3]);
          acc[0] += a0.x * a0.x; acc[1] += a0.y * a0.y;
          acc[2] += a1.x * a1.x; acc[3] += a1.y * a1.y;
          acc[4] += a2.x * a2.x; acc[5] += a2.y * a2.y;
          acc[6] += a3.x * a3.x; acc[7] += a3.y * a3.y;
        }
      }
    }
  }
  float de = invDE[e];
  __half2 o[4];
#pragma unroll
  for (int i = 0; i < 4; ++i)
    o[i] = __floats2half2_rn(sqrtf(acc[2 * i] * de), sqrtf(acc[2 * i + 1] * de));
  *(float4*)((char*)Peh + ((size_t)e << 8) + (sub << 4)) = *(const float4*)o;
}

// ------------------------------------------------------------- E2V + G + phi partials
// 4 nodes per wave (one per 16-lane group); same quad-row float4 gather of Pe rows.
__global__ __launch_bounds__(256) void e2v_kernel(const __half2* __restrict__ Peh, const float* __restrict__ X,
                                                  __half2* __restrict__ Bh,
                                                  const int* __restrict__ rowptrV,
                                                  const int* __restrict__ colE,
                                                  const float* __restrict__ invSqrtD,
                                                  const float* __restrict__ rv,
                                                  const float* __restrict__ slot0,
                                                  const float* __restrict__ slotPrev,
                                                  float* __restrict__ slotOut,
                                                  int isLast) {
  __shared__ float red[16];
  const int tid = threadIdx.x;
  const int lane = tid & 63;
  const int grp = lane >> 4;
  const int sub = lane & 15;
  const int wv = tid >> 6;
  const int v = blockIdx.x * 16 + wv * 4 + grp;   // grid 3125*16 = 50000 exact

  // wave-wide reduce of the 64 striped phi slots
  float p0 = slot0[lane];
  float pp = slotPrev[lane];
#pragma unroll
  for (int off = 32; off > 0; off >>= 1) {
    p0 += __shfl_xor(p0, off, 64);
    pp += __shfl_xor(pp, off, 64);
  }
  float s0 = 1.0f / (2.0f * sqrtf(p0));
  float sp = 1.0f / (2.0f * sqrtf(pp));

  const int beg = rowptrV[v], end = rowptrV[v + 1];
  const int cnt = end - beg;
  int cmax = cnt;
  cmax = max(cmax, __shfl_xor(cmax, 16, 64));
  cmax = max(cmax, __shfl_xor(cmax, 32, 64));

  float acc[8];
#pragma unroll
  for (int i = 0; i < 8; ++i) acc[i] = 0.f;
  const char* Pb = (const char*)Peh;

  for (int c0 = 0; c0 < cmax; c0 += 8) {
    int li = c0 + sub;
    int eidx = colE[beg + (li < cnt ? li : cnt - 1)];
    float4 r[8];
#pragma unroll
    for (int u = 0; u < 8; ++u) {
      int m = __shfl(eidx, (grp << 4) | u, 64);
      r[u] = *(const float4*)(Pb + ((size_t)m << 8) + (sub << 4));
    }
#pragma unroll
    for (int u = 0; u < 8; ++u) {
      if (c0 + u < cnt) {
        const __half2* h = (const __half2*)&r[u];
        float2 a0 = __half22float2(h[0]);
        float2 a1 = __half22float2(h[1]);
        float2 a2 = __half22float2(h[2]);
        float2 a3 = __half22float2(h[3]);
        acc[0] += a0.x; acc[1] += a0.y;
        acc[2] += a1.x; acc[3] += a1.y;
        acc[4] += a2.x; acc[5] += a2.y;
        acc[6] += a3.x; acc[7] += a3.y;
      }
    }
  }

  float isd = invSqrtD[v];
  float c1 = 0.9f * sp * isd;
  float c0w = 0.1f * s0;
  // X row slice: feats [sub*8, sub*8+8)
  const float4* xp = (const float4*)((const char*)X + ((size_t)v << 9) + (sub << 5));
  float4 x0 = xp[0], x1 = xp[1];
  float g[8];
  g[0] = c1 * acc[0] + c0w * x0.x;  g[1] = c1 * acc[1] + c0w * x0.y;
  g[2] = c1 * acc[2] + c0w * x0.z;  g[3] = c1 * acc[3] + c0w * x0.w;
  g[4] = c1 * acc[4] + c0w * x1.x;  g[5] = c1 * acc[5] + c0w * x1.y;
  g[6] = c1 * acc[6] + c0w * x1.z;  g[7] = c1 * acc[7] + c0w * x1.w;
  float q = 0.f;
  __half2 o[4];
#pragma unroll
  for (int i = 0; i < 4; ++i) {
    float b0 = g[2 * i] * isd, b1 = g[2 * i + 1] * isd;
    q += b0 * b0 + b1 * b1;
    o[i] = isLast ? __floats2half2_rn(g[2 * i], g[2 * i + 1])
                  : __floats2half2_rn(b0, b1);
  }
  *(float4*)((char*)Bh + ((size_t)v << 8) + (sub << 4)) = *(const float4*)o;

  // phi partial: reduce q over the 16 lanes of this group, then block-reduce
#pragma unroll
  for (int off = 8; off > 0; off >>= 1) q += __shfl_xor(q, off, 64);
  if (sub == 0) red[wv * 4 + grp] = q * rv[v];
  __syncthreads();
  if (tid == 0) {
    float t = 0.f;
#pragma unroll
    for (int i = 0; i < 16; ++i) t += red[i];
    atomicAdd(&slotOut[blockIdx.x & 63], t);
  }
}

// ------------------------------------------------------------- fused decoder
// 512 threads, 64 nodes/block. GEMM1 f32 reg-tiled + LN + ReLU + GEMM2 with b128 LDS reads.
__global__ __launch_bounds__(512) void decoder_kernel(const __half2* __restrict__ Gh,
                                                      const float* __restrict__ slot10,
                                                      const float* __restrict__ W1, const float* __restrict__ b1,
                                                      const float* __restrict__ gam, const float* __restrict__ bet,
                                                      const float* __restrict__ W2, const float* __restrict__ b2,
                                                      float* __restrict__ out) {
  __shared__ float smem[8192];            // 32 KB
  float* Ft = smem;
  const int tid = threadIdx.x;
  const int lane = tid & 63;
  const int node0 = blockIdx.x * 64;

  float ps = slot10[lane];
#pragma unroll
  for (int off = 32; off > 0; off >>= 1) ps += __shfl_xor(ps, off, 64);
  const float s = 1.0f / (2.0f * sqrtf(ps));   // 1/phi(G10)

  for (int i = tid; i < 4096; i += 512) {       // 64 rows x 64 half2
    int nd = i >> 6, c2 = i & 63;
    float2 f = make_float2(0.f, 0.f);
    if (node0 + nd < N_NODES) {
      float2 g = __half22float2(Gh[((size_t)(node0 + nd)) * 64 + c2]);
      f.x = g.x * s; f.y = g.y * s;
    }
    *(float2*)(&Ft[nd * 128 + c2 * 2]) = f;
  }
  __syncthreads();

  const int rt = tid >> 5;                 // 0..15 -> node group of 4
  const int ct = tid & 31;                 // 0..31 -> hid group of 8
  float bias[8], g8[8], be8[8];
#pragma unroll
  for (int j = 0; j < 8; ++j) {
    bias[j] = b1[ct * 8 + j];
    g8[j] = gam[ct * 8 + j];
    be8[j] = bet[ct * 8 + j];
  }
  float acc[4][8];
#pragma unroll
  for (int i = 0; i < 4; ++i)
#pragma unroll
    for (int j = 0; j < 8; ++j) acc[i][j] = bias[j];

  for (int k4 = 0; k4 < 32; ++k4) {
    float4 a4[4];
#pragma unroll
    for (int i = 0; i < 4; ++i) a4[i] = *(const float4*)(&Ft[(rt * 4 + i) * 128 + k4 * 4]);
#pragma unroll
    for (int kk = 0; kk < 4; ++kk) {
      const float* wrow = W1 + (k4 * 4 + kk) * HID + ct * 8;
      float4 b0 = *(const float4*)(wrow);
      float4 b1v = *(const float4*)(wrow + 4);
      float bb[8] = {b0.x, b0.y, b0.z, b0.w, b1v.x, b1v.y, b1v.z, b1v.w};
#pragma unroll
      for (int i = 0; i < 4; ++i) {
        float av = (kk == 0) ? a4[i].x : (kk == 1) ? a4[i].y : (kk == 2) ? a4[i].z : a4[i].w;
#pragma unroll
        for (int j = 0; j < 8; ++j) acc[i][j] += av * bb[j];
      }
    }
  }

  // LayerNorm + ReLU (32 lanes sharing rt hold one row)
#pragma unroll
  for (int i = 0; i < 4; ++i) {
    float s1 = 0.f, s2 = 0.f;
#pragma unroll
    for (int j = 0; j < 8; ++j) { s1 += acc[i][j]; s2 += acc[i][j] * acc[i][j]; }
#pragma unroll
    for (int off = 16; off > 0; off >>= 1) {
      s1 += __shfl_xor(s1, off, 64);
      s2 += __shfl_xor(s2, off, 64);
    }
    float mu = s1 * (1.0f / 256.0f);
    float var = s2 * (1.0f / 256.0f) - mu * mu;
    float rs = rsqrtf(var + 1e-5f);
#pragma unroll
    for (int j = 0; j < 8; ++j)
      acc[i][j] = fmaxf(0.0f, (acc[i][j] - mu) * rs * g8[j] + be8[j]);
  }
  __syncthreads();   // Ftile dead

  float* hch = smem;                       // [64][68] chunk of h (17,408 B)
  float* W2cT = smem + 64 * 68;            // [40][68] transposed W2 chunk (10,880 B)

  const int n_l = tid >> 3;                // node 0..63
  const int og = tid & 7;                  // 8 groups of 5 outputs
  float oacc[5];
#pragma unroll
  for (int j = 0; j < 5; ++j) oacc[j] = b2[og * 5 + j];

  for (int c = 0; c < 4; ++c) {            // 4 chunks of 64 hid dims
    for (int i = tid; i < 64 * NOUT; i += 512) {
      int j = i >> 6, kk = i & 63;
      W2cT[j * 68 + kk] = W2[(c * 64 + kk) * NOUT + j];
    }
    if ((ct >> 3) == c) {
      int c8 = (ct & 7) * 8;
#pragma unroll
      for (int i = 0; i < 4; ++i)
#pragma unroll
        for (int j = 0; j < 8; ++j) hch[(rt * 4 + i) * 68 + c8 + j] = acc[i][j];
    }
    __syncthreads();
    for (int kk4 = 0; kk4 < 16; ++kk4) {
      float4 h4 = *(const float4*)(&hch[n_l * 68 + kk4 * 4]);
#pragma unroll
      for (int j = 0; j < 5; ++j) {
        float4 w4 = *(const float4*)(&W2cT[(og * 5 + j) * 68 + kk4 * 4]);
        oacc[j] += h4.x * w4.x + h4.y * w4.y + h4.z * w4.z + h4.w * w4.w;
      }
    }
    __syncthreads();
  }

  int node = node0 + n_l;
  if (node < N_NODES) {
#pragma unroll
    for (int j = 0; j < 5; ++j) out[(size_t)node * NOUT + og * 5 + j] = oacc[j];
  }
}

// ---------------------------------------------------------------- launch
extern "C" void kernel_launch(void* const* d_in, const int* in_sizes, int n_in,
                              void* d_out, int out_size, void* d_ws, size_t ws_size,
                              hipStream_t stream) {
  (void)in_sizes; (void)n_in; (void)out_size; (void)ws_size;
  const float* x = (const float*)d_in[0];
  const int* he = (const int*)d_in[1];
  const int* V = he;
  const int* E = he + NNZ_TOT;
  const float* W1 = (const float*)d_in[2];
  const float* b1 = (const float*)d_in[3];
  const float* gam = (const float*)d_in[4];
  const float* bet = (const float*)d_in[5];
  const float* W2 = (const float*)d_in[6];
  const float* b2 = (const float*)d_in[7];
  float* out = (float*)d_out;

  // Peh (2.56 MB fp16) lives in d_out (8 MB): dead before decoder (sole d_out writer) runs.
  __half2* Peh = (__half2*)d_out;

  char* p = (char*)d_ws;
  auto nextp = [&](size_t bytes) -> char* {
    char* r = p;
    p += (bytes + 255) & ~(size_t)255;
    return r;
  };
  int* cntV      = (int*)nextp((size_t)(N_NODES + M_EDGES) * 4 + 11 * 64 * 4);
  int* cntE      = cntV + N_NODES;
  float* phis    = (float*)(cntE + M_EDGES);     // [11][64] striped phi partials
  int* rowptrV   = (int*)nextp((size_t)(N_NODES + 1) * 4);
  int* rowptrE   = (int*)nextp((size_t)(M_EDGES + 1) * 4);
  int* colE      = (int*)nextp((size_t)NNZ_TOT * 4);
  int* colV      = (int*)nextp((size_t)NNZ_TOT * 4);
  float* invSqrtD= (float*)nextp((size_t)N_NODES * 4);
  float* rv      = (float*)nextp((size_t)N_NODES * 4);
  float* invDE   = (float*)nextp((size_t)M_EDGES * 4);
  __half2* Bh    = (__half2*)nextp((size_t)N_NODES * DF * 2);   // fp16 iterate, 12.8 MB

  const int NBLK_NNZ = (NNZ_TOT + 255) / 256;

  hipMemsetAsync(cntV, 0, (size_t)(N_NODES + M_EDGES) * 4 + 11 * 64 * 4, stream);
  count_kernel<<<NBLK_NNZ, 256, 0, stream>>>(V, E, cntV, cntE);
  scan_kernel<<<1, 1024, 0, stream>>>(cntV, N_NODES, rowptrV);
  scan_kernel<<<1, 1024, 0, stream>>>(cntE, M_EDGES, rowptrE);
  fill_kernel<<<NBLK_NNZ, 256, 0, stream>>>(V, E, cntV, cntE, colE, colV);
  edge_stats_kernel<<<(M_EDGES + 255) / 256, 256, 0, stream>>>(rowptrE, invDE);
  node_stats_kernel<<<(N_NODES + 255) / 256, 256, 0, stream>>>(rowptrV, colE, invDE, invSqrtD, rv);
  phi0_kernel<<<N_NODES / 4, 256, 0, stream>>>(x, invSqrtD, rv, Bh, phis);

  for (int k = 1; k <= 10; ++k) {
    v2e_kernel<<<M_EDGES / 16, 256, 0, stream>>>(Bh, Peh, rowptrE, colV, invDE);
    e2v_kernel<<<N_NODES / 16, 256, 0, stream>>>(Peh, x, Bh, rowptrV, colE, invSqrtD, rv,
                                                 phis, phis + (size_t)(k - 1) * 64,
                                                 phis + (size_t)k * 64, (k == 10) ? 1 : 0);
  }

  decoder_kernel<<<(N_NODES + 63) / 64, 512, 0, stream>>>(Bh, phis + 640, W1, b1, gam, bet, W2, b2, out);
}